// Round 1
// baseline (229.937 us; speedup 1.0000x reference)
//
#include <hip/hip_runtime.h>
#include <hip/hip_bf16.h>

typedef unsigned short u16;
typedef short bf16x8 __attribute__((ext_vector_type(8)));
typedef float f32x4 __attribute__((ext_vector_type(4)));

#define NROWS 8192
#define EMBD  1140
#define FDIM  3968   // 32*124
#define N1R   1000
#define N1P   1024
#define N2R   100
#define N2P   128
#define DG    512

__device__ inline u16 f2b(float f) {
  __hip_bfloat16 h = __float2bfloat16(f);
  return *reinterpret_cast<u16*>(&h);
}

// ---------------- conversion kernels ----------------
__global__ void cvt_pad2_kernel(const float* __restrict__ in, u16* __restrict__ out,
                                int realN, int realK, int NP, int KP) {
  long total = (long)NP * KP;
  long stride = (long)gridDim.x * blockDim.x;
  for (long i = (long)blockIdx.x * blockDim.x + threadIdx.x; i < total; i += stride) {
    int n = (int)(i / KP);
    int k = (int)(i - (long)n * KP);
    float v = (n < realN && k < realK) ? in[(long)n * realK + k] : 0.f;
    out[i] = f2b(v);
  }
}

__global__ void cvt_kernel(const float4* __restrict__ in, ushort4* __restrict__ out, long n4) {
  long stride = (long)gridDim.x * blockDim.x;
  for (long i = (long)blockIdx.x * blockDim.x + threadIdx.x; i < n4; i += stride) {
    float4 v = in[i];
    ushort4 o;
    o.x = f2b(v.x); o.y = f2b(v.y); o.z = f2b(v.z); o.w = f2b(v.w);
    out[i] = o;
  }
}

// ---------------- separable conv precompute ----------------
// A[i][f] = sum_kw conv_w[o][0][0][kw]*H_emb[i][9w+kw] + conv_b[o]   (i < 240)
// B[j][f] = sum_kw conv_w[o][0][1][kw]*H_emb[240+j][9w+kw]           (j < 404)
__global__ __launch_bounds__(256) void precomp_ab_kernel(
    const float* __restrict__ H_emb, const float* __restrict__ conv_w,
    const float* __restrict__ conv_b, float* __restrict__ Abuf, float* __restrict__ Bbuf) {
  int b = blockIdx.x;
  bool isA = b < 240;
  const float* emb = H_emb + (size_t)b * EMBD;   // row index == b in both cases
  float* outp = isA ? (Abuf + (size_t)b * FDIM) : (Bbuf + (size_t)(b - 240) * FDIM);
  __shared__ float se[EMBD];
  __shared__ float sw[32 * 25];
  __shared__ float sb[32];
  int t = threadIdx.x;
  for (int i = t; i < EMBD; i += 256) se[i] = emb[i];
  int kh = isA ? 0 : 1;
  for (int i = t; i < 800; i += 256) {
    int o = i / 25, kw = i - o * 25;
    sw[i] = conv_w[o * 50 + kh * 25 + kw];
  }
  if (t < 32) sb[t] = isA ? conv_b[t] : 0.f;
  __syncthreads();
  for (int f = t; f < FDIM; f += 256) {
    int o = f / 124, wpos = f - o * 124;
    const float* e = se + wpos * 9;
    const float* wp = sw + o * 25;
    float acc = sb[o];
#pragma unroll
    for (int kw = 0; kw < 25; ++kw) acc += wp[kw] * e[kw];
    outp[f] = acc;
  }
}

// c[r][f] = lrelu(A[x[r]][f] + B[y[r]][f])  -> bf16
__global__ __launch_bounds__(256) void conv_combine_kernel(
    const float* __restrict__ Abuf, const float* __restrict__ Bbuf,
    const int* __restrict__ xi, const int* __restrict__ yi, u16* __restrict__ cbf) {
  int r = blockIdx.x;
  const float4* pa = (const float4*)(Abuf + (size_t)xi[r] * FDIM);
  const float4* pb = (const float4*)(Bbuf + (size_t)yi[r] * FDIM);
  u16* out = cbf + (size_t)r * FDIM;
  for (int i = threadIdx.x; i < FDIM / 4; i += 256) {
    float4 a = pa[i], b = pb[i];
    float v0 = a.x + b.x, v1 = a.y + b.y, v2 = a.z + b.z, v3 = a.w + b.w;
    v0 = v0 > 0.f ? v0 : 0.01f * v0;
    v1 = v1 > 0.f ? v1 : 0.01f * v1;
    v2 = v2 > 0.f ? v2 : 0.01f * v2;
    v3 = v3 > 0.f ? v3 : 0.01f * v3;
    ushort4 o;
    o.x = f2b(v0); o.y = f2b(v1); o.z = f2b(v2); o.w = f2b(v3);
    *(ushort4*)(out + i * 4) = o;
  }
}

// ---------------- bf16 MFMA GEMM: C[m][n] = epi(sum_k A[m][k]*B[n][k] + bias[n]) ----------------
// 128x128 tile, 4 waves (2x2 of 64x64), BK=32, reg-staged with next-tile prefetch,
// XOR-swizzled LDS (same swizzle on write+read => correctness-safe, kills bank conflicts).
template<int EPI, int OUTBF>   // EPI: 0=lrelu 1=tanh
__global__ __launch_bounds__(256) void gemm_bt_kernel(
    const u16* __restrict__ A, const u16* __restrict__ B,
    const float* __restrict__ bias, int realN,
    void* __restrict__ C, int K, int ldc) {
  const int tm = blockIdx.y * 128;
  const int tn = blockIdx.x * 128;
  __shared__ u16 As[128 * 32];
  __shared__ u16 Bs[128 * 32];
  const int t = threadIdx.x;
  const int lane = t & 63;
  const int w = t >> 6;
  const int wr = (w >> 1) * 64, wc = (w & 1) * 64;
  const int srow = t >> 2;           // 0..63 (rows 0-63 chunk; +64 for second chunk)
  const int scolB = (t & 3) * 16;    // byte offset of this thread's 16B within a 64B row

  const size_t aBase  = (size_t)(tm + srow) * K + (scolB >> 1);
  const size_t a2Base = (size_t)(tm + 64 + srow) * K + (scolB >> 1);
  const size_t bBase  = (size_t)(tn + srow) * K + (scolB >> 1);
  const size_t b2Base = (size_t)(tn + 64 + srow) * K + (scolB >> 1);
  const int sw0 = (srow * 64 + scolB) ^ ((srow & 7) << 4);
  const int sw1 = ((srow + 64) * 64 + scolB) ^ ((srow & 7) << 4);

  const int fr = lane & 15;
  const int kg = lane >> 4;

  f32x4 acc[4][4];
#pragma unroll
  for (int m = 0; m < 4; ++m)
#pragma unroll
    for (int n = 0; n < 4; ++n) acc[m][n] = (f32x4){0.f, 0.f, 0.f, 0.f};

  const int nk = K >> 5;
  int4 ra0 = *(const int4*)(A + aBase);
  int4 ra1 = *(const int4*)(A + a2Base);
  int4 rb0 = *(const int4*)(B + bBase);
  int4 rb1 = *(const int4*)(B + b2Base);

  for (int kt = 0; kt < nk; ++kt) {
    __syncthreads();
    *(int4*)((char*)As + sw0) = ra0;
    *(int4*)((char*)As + sw1) = ra1;
    *(int4*)((char*)Bs + sw0) = rb0;
    *(int4*)((char*)Bs + sw1) = rb1;
    __syncthreads();
    if (kt + 1 < nk) {
      const int ko = (kt + 1) * 32;
      ra0 = *(const int4*)(A + aBase + ko);
      ra1 = *(const int4*)(A + a2Base + ko);
      rb0 = *(const int4*)(B + bBase + ko);
      rb1 = *(const int4*)(B + b2Base + ko);
    }
    bf16x8 af[4], bff[4];
#pragma unroll
    for (int m = 0; m < 4; ++m) {
      int row = wr + m * 16 + fr;
      af[m] = *(const bf16x8*)((const char*)As + ((row * 64 + kg * 16) ^ ((row & 7) << 4)));
    }
#pragma unroll
    for (int n = 0; n < 4; ++n) {
      int row = wc + n * 16 + fr;
      bff[n] = *(const bf16x8*)((const char*)Bs + ((row * 64 + kg * 16) ^ ((row & 7) << 4)));
    }
#pragma unroll
    for (int m = 0; m < 4; ++m)
#pragma unroll
      for (int n = 0; n < 4; ++n)
        acc[m][n] = __builtin_amdgcn_mfma_f32_16x16x32_bf16(af[m], bff[n], acc[m][n], 0, 0, 0);
  }

  // epilogue: C/D layout col = lane&15, row = (lane>>4)*4 + j   [verified m89/m91]
#pragma unroll
  for (int n = 0; n < 4; ++n) {
    int col = tn + wc + n * 16 + fr;
    float bv = (col < realN) ? bias[col] : 0.f;
#pragma unroll
    for (int m = 0; m < 4; ++m) {
#pragma unroll
      for (int j = 0; j < 4; ++j) {
        int row = tm + wr + m * 16 + kg * 4 + j;
        float v = acc[m][n][j] + bv;
        if (EPI == 0) v = v > 0.f ? v : 0.01f * v;
        else          v = tanhf(v);
        if (OUTBF) ((u16*)C)[(size_t)row * ldc + col] = f2b(v);
        else       ((float*)C)[(size_t)row * ldc + col] = v;
      }
    }
  }
}

// ---------------- finalize: dots + softmax + scale ----------------
__global__ __launch_bounds__(256) void finalize_kernel(
    const float* __restrict__ hfc2, const float* __restrict__ g, const float* __restrict__ e,
    const float* __restrict__ ld_gcn, const float* __restrict__ ld_enc,
    float* __restrict__ out0, float* __restrict__ out1) {
  int row = blockIdx.x * 4 + (threadIdx.x >> 6);
  int lane = threadIdx.x & 63;
  const float* h = hfc2 + (size_t)row * N2P;
  const float* gg = g + (size_t)row * N2P;
  const float* ee = e + (size_t)row * N2P;
  float ag = 0.f, ae = 0.f;
#pragma unroll
  for (int i = lane; i < N2P; i += 64) {
    float hv = h[i];
    ag += gg[i] * hv;
    ae += ee[i] * hv;
  }
#pragma unroll
  for (int off = 32; off; off >>= 1) {
    ag += __shfl_xor(ag, off);
    ae += __shfl_xor(ae, off);
  }
  float m = fmaxf(ag, ae);
  float eg = expf(ag - m), eo = expf(ae - m);
  float inv = 1.f / (eg + eo);
  float wg = eg * inv, we = eo * inv;
  const float4* pg = (const float4*)(ld_gcn + (size_t)row * DG);
  const float4* pe = (const float4*)(ld_enc + (size_t)row * DG);
  float4* o0 = (float4*)(out0 + (size_t)row * DG);
  float4* o1 = (float4*)(out1 + (size_t)row * DG);
#pragma unroll
  for (int i = lane; i < DG / 4; i += 64) {
    float4 a = pg[i];
    a.x *= wg; a.y *= wg; a.z *= wg; a.w *= wg;
    o0[i] = a;
    float4 b = pe[i];
    b.x *= we; b.y *= we; b.z *= we; b.w *= we;
    o1[i] = b;
  }
}

extern "C" void kernel_launch(void* const* d_in, const int* in_sizes, int n_in,
                              void* d_out, int out_size, void* d_ws, size_t ws_size,
                              hipStream_t stream) {
  const float* ld_gcn = (const float*)d_in[0];
  const float* ld_enc = (const float*)d_in[1];
  const int*   xi     = (const int*)d_in[2];
  const int*   yi     = (const int*)d_in[3];
  const float* H_emb  = (const float*)d_in[4];
  const float* conv_w = (const float*)d_in[5];
  const float* conv_b = (const float*)d_in[6];
  const float* W1     = (const float*)d_in[7];
  const float* b1     = (const float*)d_in[8];
  const float* W2     = (const float*)d_in[9];
  const float* b2     = (const float*)d_in[10];
  const float* Wg     = (const float*)d_in[11];
  const float* bg     = (const float*)d_in[12];
  const float* We     = (const float*)d_in[13];
  const float* be     = (const float*)d_in[14];

  char* ws = (char*)d_ws;
  size_t off = 0;
  auto alloc = [&](size_t bytes) -> void* {
    void* p = ws + off;
    off = (off + bytes + 255) & ~(size_t)255;
    return p;
  };
  float* Abuf  = (float*)alloc(240ull * FDIM * 4);
  float* Bbuf  = (float*)alloc(404ull * FDIM * 4);
  u16*   cbf   = (u16*)  alloc((size_t)NROWS * FDIM * 2);
  u16*   W1bf  = (u16*)  alloc((size_t)N1P * FDIM * 2);
  u16*   W2bf  = (u16*)  alloc((size_t)N2P * N1P * 2);
  u16*   Wgbf  = (u16*)  alloc((size_t)N2P * DG * 2);
  u16*   Webf  = (u16*)  alloc((size_t)N2P * DG * 2);
  u16*   gcnbf = (u16*)  alloc((size_t)NROWS * DG * 2);
  u16*   encbf = (u16*)  alloc((size_t)NROWS * DG * 2);
  u16*   hfc1  = (u16*)  alloc((size_t)NROWS * N1P * 2);
  float* hfc2  = (float*)alloc((size_t)NROWS * N2P * 4);
  float* gbuf  = (float*)alloc((size_t)NROWS * N2P * 4);
  float* ebuf  = (float*)alloc((size_t)NROWS * N2P * 4);
  if (ws_size < off) return;  // ~130 MB needed

  cvt_pad2_kernel<<<4096, 256, 0, stream>>>(W1, W1bf, N1R, FDIM, N1P, FDIM);
  cvt_pad2_kernel<<<512, 256, 0, stream>>>(W2, W2bf, N2R, N1R, N2P, N1P);
  cvt_pad2_kernel<<<256, 256, 0, stream>>>(Wg, Wgbf, N2R, DG, N2P, DG);
  cvt_pad2_kernel<<<256, 256, 0, stream>>>(We, Webf, N2R, DG, N2P, DG);
  cvt_kernel<<<2048, 256, 0, stream>>>((const float4*)ld_gcn, (ushort4*)gcnbf, (long)NROWS * DG / 4);
  cvt_kernel<<<2048, 256, 0, stream>>>((const float4*)ld_enc, (ushort4*)encbf, (long)NROWS * DG / 4);
  precomp_ab_kernel<<<644, 256, 0, stream>>>(H_emb, conv_w, conv_b, Abuf, Bbuf);
  conv_combine_kernel<<<NROWS, 256, 0, stream>>>(Abuf, Bbuf, xi, yi, cbf);

  dim3 g1(N1P / 128, NROWS / 128);
  gemm_bt_kernel<0, 1><<<g1, 256, 0, stream>>>(cbf, W1bf, b1, N1R, hfc1, FDIM, N1P);
  dim3 g2(1, NROWS / 128);
  gemm_bt_kernel<0, 0><<<g2, 256, 0, stream>>>(hfc1, W2bf, b2, N2R, hfc2, N1P, N2P);
  gemm_bt_kernel<1, 0><<<g2, 256, 0, stream>>>(gcnbf, Wgbf, bg, N2R, gbuf, DG, N2P);
  gemm_bt_kernel<1, 0><<<g2, 256, 0, stream>>>(encbf, Webf, be, N2R, ebuf, DG, N2P);

  float* out0 = (float*)d_out;
  float* out1 = out0 + (size_t)NROWS * DG;
  finalize_kernel<<<NROWS / 4, 256, 0, stream>>>(hfc2, gbuf, ebuf, ld_gcn, ld_enc, out0, out1);
}